// Round 12
// baseline (1918.653 us; speedup 1.0000x reference)
//
#include <hip/hip_runtime.h>
#include <hip/hip_bf16.h>
#include <math.h>

// ---------------------------------------------------------------------------
// BiLSTM-CRF, fp32 end-to-end.
// Sizes: B=64 T=256 CHAR_E=256 POS_E=128 Hp=128, Hm=256, Dm=640, LBL=20.
// R12: main_rec = R7-exact core + runtime co-XCD pairing with a FIXED probe.
// R3/R5's probes bounded round 1 at 24-64 iters -> launch skew (~10-30us)
// always timed them out; the same-L2 sc0 path was never actually exercised.
// Two-tier bounds: round 1 = 2048 iters (skew), rounds 2-8 = 256 (steady
// state; cross-L2 stores stay dirty in writer's L2 -> reliable timeout).
// Co-XCD pairs exchange h via plain store + sc0 L2 poll (~300cy); all other
// pairs use the R2-proven relaxed agent atomics.
// ---------------------------------------------------------------------------

#define Bsz 64
#define Tsz 256
#define NROW 16384        // B*T

__device__ __forceinline__ float sigm(float x) { return 1.f / (1.f + expf(-x)); }

#define PIN4(v) asm volatile("" : "+v"((v).x), "+v"((v).y), "+v"((v).z), "+v"((v).w))

// L1-bypass 8B load: reads the XCD's shared L2 directly (sc0 = L1 bypass).
__device__ __forceinline__ unsigned long long l2_poll(const unsigned long long* p) {
  unsigned long long v;
  asm volatile("global_load_dwordx2 %0, %1, off sc0\n\t"
               "s_waitcnt vmcnt(0)"
               : "=&v"(v) : "v"(p) : "memory");
  return v;
}

// ------------------------- gather: embeddings --------------------------------
__global__ __launch_bounds__(256) void gather_kernel(
    const int* __restrict__ ci, const int* __restrict__ pi, const int* __restrict__ ti,
    const float* __restrict__ ce, const float* __restrict__ pe, const float* __restrict__ te,
    float* __restrict__ tbuf, float* __restrict__ emb) {
  int gid = blockIdx.x * 256 + threadIdx.x;     // NROW*128 threads
  int m = gid >> 7, s = gid & 127;
  if (s < 32) {
    ((float4*)&tbuf[(size_t)m * 128])[s] = ((const float4*)&te[(size_t)ti[m] * 128])[s];
  } else if (s < 96) {
    ((float4*)&emb[(size_t)m * 640])[s - 32] = ((const float4*)&ce[(size_t)ci[m] * 256])[s - 32];
  } else {
    ((float4*)&emb[(size_t)m * 640 + 256])[s - 96] = ((const float4*)&pe[(size_t)pi[m] * 128])[s - 96];
  }
}

// ------------------- fp32 tiled GEMM: C[m,n] = A[m,:].B[n,:] + bias[n] -------
// Double-buffered LDS, one barrier per k-tile. K must be a multiple of 16.
#define GBM 128
#define GBN 128
#define GBK 16
__global__ __launch_bounds__(256) void gemm_nt(
    const float* __restrict__ A, int lda,
    const float* __restrict__ B, int ldb,
    const float* __restrict__ bias,
    float* __restrict__ C, int ldc, int col0, int K) {
  __shared__ __align__(16) float As[2][GBK][GBM + 4];
  __shared__ __align__(16) float Bs[2][GBK][GBN + 4];
  const int tid = threadIdx.x;
  const int tx = tid & 15, ty = tid >> 4;
  const int m0 = blockIdx.y * GBM, n0 = blockIdx.x * GBN;
  const int row0 = tid >> 2, kq = (tid & 3) * 4;
  const int row1 = row0 + 64;
  const float* Ar0 = &A[(size_t)(m0 + row0) * lda + kq];
  const float* Ar1 = &A[(size_t)(m0 + row1) * lda + kq];
  const float* Br0 = &B[(size_t)(n0 + row0) * ldb + kq];
  const float* Br1 = &B[(size_t)(n0 + row1) * ldb + kq];

  float acc[8][8] = {};
  float4 a0 = *(const float4*)Ar0;
  float4 a1 = *(const float4*)Ar1;
  float4 b0 = *(const float4*)Br0;
  float4 b1 = *(const float4*)Br1;
  int buf = 0;
  As[0][kq + 0][row0] = a0.x; As[0][kq + 1][row0] = a0.y; As[0][kq + 2][row0] = a0.z; As[0][kq + 3][row0] = a0.w;
  As[0][kq + 0][row1] = a1.x; As[0][kq + 1][row1] = a1.y; As[0][kq + 2][row1] = a1.z; As[0][kq + 3][row1] = a1.w;
  Bs[0][kq + 0][row0] = b0.x; Bs[0][kq + 1][row0] = b0.y; Bs[0][kq + 2][row0] = b0.z; Bs[0][kq + 3][row0] = b0.w;
  Bs[0][kq + 0][row1] = b1.x; Bs[0][kq + 1][row1] = b1.y; Bs[0][kq + 2][row1] = b1.z; Bs[0][kq + 3][row1] = b1.w;
  __syncthreads();

  for (int k0 = 0; k0 < K; k0 += GBK) {
    const bool more = (k0 + GBK) < K;
    if (more) {
      a0 = *(const float4*)(Ar0 + k0 + GBK);
      a1 = *(const float4*)(Ar1 + k0 + GBK);
      b0 = *(const float4*)(Br0 + k0 + GBK);
      b1 = *(const float4*)(Br1 + k0 + GBK);
    }
#pragma unroll
    for (int kk = 0; kk < GBK; ++kk) {
      float4 x0 = *(const float4*)&As[buf][kk][ty * 8];
      float4 x1 = *(const float4*)&As[buf][kk][ty * 8 + 4];
      float4 y0 = *(const float4*)&Bs[buf][kk][tx * 8];
      float4 y1 = *(const float4*)&Bs[buf][kk][tx * 8 + 4];
      float av[8] = {x0.x, x0.y, x0.z, x0.w, x1.x, x1.y, x1.z, x1.w};
      float bv[8] = {y0.x, y0.y, y0.z, y0.w, y1.x, y1.y, y1.z, y1.w};
#pragma unroll
      for (int i = 0; i < 8; ++i)
#pragma unroll
        for (int jj = 0; jj < 8; ++jj) acc[i][jj] = fmaf(av[i], bv[jj], acc[i][jj]);
    }
    if (more) {
      buf ^= 1;
      As[buf][kq + 0][row0] = a0.x; As[buf][kq + 1][row0] = a0.y; As[buf][kq + 2][row0] = a0.z; As[buf][kq + 3][row0] = a0.w;
      As[buf][kq + 0][row1] = a1.x; As[buf][kq + 1][row1] = a1.y; As[buf][kq + 2][row1] = a1.z; As[buf][kq + 3][row1] = a1.w;
      Bs[buf][kq + 0][row0] = b0.x; Bs[buf][kq + 1][row0] = b0.y; Bs[buf][kq + 2][row0] = b0.z; Bs[buf][kq + 3][row0] = b0.w;
      Bs[buf][kq + 0][row1] = b1.x; Bs[buf][kq + 1][row1] = b1.y; Bs[buf][kq + 2][row1] = b1.z; Bs[buf][kq + 3][row1] = b1.w;
      __syncthreads();
    }
  }
#pragma unroll
  for (int i = 0; i < 8; ++i) {
    size_t m = m0 + ty * 8 + i;
    int nb = n0 + tx * 8;
    float4 o0 = {acc[i][0] + bias[nb+0], acc[i][1] + bias[nb+1], acc[i][2] + bias[nb+2], acc[i][3] + bias[nb+3]};
    float4 o1 = {acc[i][4] + bias[nb+4], acc[i][5] + bias[nb+5], acc[i][6] + bias[nb+6], acc[i][7] + bias[nb+7]};
    *(float4*)&C[m * ldc + col0 + nb]     = o0;
    *(float4*)&C[m * ldc + col0 + nb + 4] = o1;
  }
}

// --------------------------- pos BiLSTM recurrence ---------------------------
// 128 blocks (b, dir). 512 threads = 512 gate rows; Whh [512][128] pinned via
// asm-opaque (cures compiler loop-invariant-load sinking). R7-proven.
__global__ __launch_bounds__(512, 2) void pos_rec(
    const int* __restrict__ lengths, const float* __restrict__ gpos,
    const float* __restrict__ Wf, const float* __restrict__ Wb,
    float* __restrict__ emb) {
  const int blk = blockIdx.x;
  const int b = blk >> 1, dir = blk & 1;
  const int j = threadIdx.x;
  const int gc = j >> 7;
  const int len = lengths[b];
  const float* W = dir ? Wb : Wf;
  __shared__ __align__(16) float h[128];
  __shared__ float gbuf[512];
  float4 w4[32];
#pragma unroll
  for (int i = 0; i < 32; ++i) w4[i] = *(const float4*)&W[(size_t)j * 128 + i * 4];
#pragma unroll
  for (int i = 0; i < 32; ++i) PIN4(w4[i]);
  float c = 0.f;
  if (j < 128) h[j] = 0.f;
  __syncthreads();
  int idx0 = dir ? (len - 1) : 0;
  float gcur = gpos[((size_t)(b * Tsz + idx0)) * 1024 + dir * 512 + j];
  for (int t = 0; t < len; ++t) {
    const int idx = dir ? (len - 1 - t) : t;
    const int tn = (t + 1 < len) ? t + 1 : t;
    const int idxn = dir ? (len - 1 - tn) : tn;
    float gnext = gpos[((size_t)(b * Tsz + idxn)) * 1024 + dir * 512 + j];
    float acc = gcur;
    const float4* h4 = (const float4*)h;
#pragma unroll
    for (int i = 0; i < 32; ++i) {
      float4 hh = h4[i];
      acc = fmaf(hh.x, w4[i].x, acc); acc = fmaf(hh.y, w4[i].y, acc);
      acc = fmaf(hh.z, w4[i].z, acc); acc = fmaf(hh.w, w4[i].w, acc);
    }
    gbuf[j] = (gc == 2) ? tanhf(acc) : sigm(acc);
    __syncthreads();
    if (j < 128) {
      float si = gbuf[j], sf = gbuf[128 + j], tg = gbuf[256 + j], so = gbuf[384 + j];
      c = sf * c + si * tg;
      float hn = so * tanhf(c);
      h[j] = hn;
      emb[((size_t)(b * Tsz + idx)) * 640 + 384 + dir * 128 + j] = hn;
    }
    __syncthreads();
    gcur = gnext;
  }
}

// --------------------------- main BiLSTM recurrence --------------------------
// 256 blocks. Runtime XCD discovery (s_getreg XCC_ID) -> deterministic co-XCD
// pairing -> two-tier handshake probe -> FAST (plain store + sc0 L2 poll) or
// SLOW (R2-proven relaxed agent atomics). Core = R7-exact:
// weights/thread: 40 f4 PINNED VGPR (k 0..159), 19 f4 LDS (k 160..235),
// 5 f4 compiler-choice (k 236..255). Per step: matvec -> act -> barrier ->
// w01: gates -> h -> store -> lstm_out -> poll partner -> barrier.
#define MR_VF4 40
#define MR_LF4 19
#define MR_TF4 5
#define HX_STRIDE 320      // ull/block: data 0..255, probe 288, decision 304
#define PROBE_SLOT 288
#define DEC_SLOT 304
__global__ __launch_bounds__(512, 2) void main_rec(
    const int* __restrict__ lengths, const float* __restrict__ gmain,
    const float* __restrict__ Wf, const float* __restrict__ Wb,
    float* __restrict__ lstm_out, unsigned long long* __restrict__ hx,
    unsigned long long* __restrict__ xinfo) {
  extern __shared__ float smem[];
  float4* wl  = (float4*)smem;                    // [MR_LF4*512] float4
  float* hbuf = smem + MR_LF4 * 512 * 4;          // 256 (full h, absolute idx)
  float* gbuf = hbuf + 256;                       // 512
  int*   xl   = (int*)gbuf;                       // discovery scratch (reuses gbuf)
  int*   asg  = xl + 256;                         // 4 ints: chain, half, part, fast

  const int blk = blockIdx.x;
  const int j = threadIdx.x;
  const int gc = j >> 7, ul = j & 127;

  // ---- phase A: publish my XCD id; gather all 256 (1 block/CU, co-resident) ----
  int xcc;
  asm volatile("s_getreg_b32 %0, hwreg(HW_REG_XCC_ID)" : "=s"(xcc));
  xcc &= 7;
  if (j == 0)
    __hip_atomic_store(&xinfo[blk], 0x100ull | (unsigned long long)xcc,
                       __ATOMIC_RELAXED, __HIP_MEMORY_SCOPE_AGENT);
  if (j < 256) {
    unsigned long long v; long guard = 0;
    for (;;) {
      v = __hip_atomic_load(&xinfo[j], __ATOMIC_RELAXED, __HIP_MEMORY_SCOPE_AGENT);
      if (v & 0x100ull) break;
      if (++guard > (1L << 26)) { v = 0x100ull; break; }  // deadlock valve
      __builtin_amdgcn_s_sleep(2);
    }
    xl[j] = (int)(v & 7ull);
  }
  __syncthreads();

  // ---- phase B: deterministic pairing (identical in every block) ----
  if (j == 0) {
    int myChain = -1, myHalf = 0, myPart = 0, myFast = 0;
    int pc = 0, leftover[8], nl = 0;
    for (int x = 0; x < 8; ++x) {
      int prev = -1;
      for (int i = 0; i < 256; ++i) {
        if (xl[i] != x) continue;
        if (prev < 0) { prev = i; }
        else {
          if (prev == blk || i == blk) {
            myChain = pc; myHalf = (i == blk); myPart = (prev == blk) ? i : prev; myFast = 1;
          }
          ++pc; prev = -1;
        }
      }
      if (prev >= 0 && nl < 8) leftover[nl++] = prev;
    }
    for (int k = 0; k + 1 < nl; k += 2) {
      int a = leftover[k], c2 = leftover[k + 1];
      if (a == blk || c2 == blk) {
        myChain = pc; myHalf = (c2 == blk); myPart = (c2 == blk) ? a : c2; myFast = 0;
      }
      ++pc;
    }
    asg[0] = myChain; asg[1] = myHalf; asg[2] = myPart; asg[3] = myFast;
  }
  __syncthreads();
  const int chain = asg[0], half = asg[1], part = asg[2];
  const int b = chain >> 1, dir = chain & 1;
  const int len = lengths[b];

  unsigned long long* selfD = hx + (size_t)blk * HX_STRIDE;
  unsigned long long* partD = hx + (size_t)part * HX_STRIDE;

  // ---- phase C: two-tier probe (round 1 covers launch skew; 2-8 are tight) ----
  if (j == 0) {
    int ok = asg[3];
    if (ok) {
      for (int k = 1; k <= 8 && ok; ++k) {
        __hip_atomic_store(&selfD[PROBE_SLOT], (0xABCull << 32) | (unsigned)k,
                           __ATOMIC_RELAXED, __HIP_MEMORY_SCOPE_WORKGROUP);
        const int bound = (k == 1) ? 2048 : 256;
        int it = 0;
        for (;;) {
          unsigned long long v = l2_poll(&partD[PROBE_SLOT]);
          if ((v >> 32) == 0xABCull && (unsigned)v >= (unsigned)k) break;
          if (++it > bound) { ok = 0; break; }
        }
      }
      // consensus with partner via the proven agent-atomic path
      __hip_atomic_store(&selfD[DEC_SLOT], (0x515ull << 32) | (unsigned)(ok + 1),
                         __ATOMIC_RELAXED, __HIP_MEMORY_SCOPE_AGENT);
      unsigned long long pv; long g2 = 0;
      for (;;) {
        pv = __hip_atomic_load(&partD[DEC_SLOT], __ATOMIC_RELAXED, __HIP_MEMORY_SCOPE_AGENT);
        if ((pv >> 32) == 0x515ull) break;
        if (++g2 > (1L << 24)) { pv = (0x515ull << 32) | 1ull; break; }
        __builtin_amdgcn_s_sleep(2);
      }
      ok = ok & ((int)(pv & 0xffffffffull) - 1);
    }
    asg[3] = ok;
  }
  __syncthreads();
  const int fast = asg[3];

  // ---- R7-exact core ----
  const int r = gc * 256 + half * 128 + ul;        // gate row in [0,1024)
  const float* Wr = (dir ? Wb : Wf) + (size_t)r * 256;
  const int obase = dir * 256 + half * 128;

  float4 wv[MR_VF4];
#pragma unroll
  for (int i = 0; i < MR_VF4; ++i) wv[i] = *(const float4*)&Wr[i * 4];
#pragma unroll
  for (int i = 0; i < MR_VF4; ++i) PIN4(wv[i]);
#pragma unroll
  for (int i = 0; i < MR_LF4; ++i) wl[i * 512 + j] = *(const float4*)&Wr[(MR_VF4 + i) * 4];

  float c = 0.f;
  if (j < 256) hbuf[j] = 0.f;
  __syncthreads();

  const int idx0 = dir ? (len - 1) : 0;
  float gcur = gmain[((size_t)(b * Tsz + idx0)) * 2048 + dir * 1024 + r];
  for (int t = 0; t < len; ++t) {
    const int idx = dir ? (len - 1 - t) : t;
    const int tn = (t + 1 < len) ? t + 1 : t;
    const int idxn = dir ? (len - 1 - tn) : tn;
    float gnext = gmain[((size_t)(b * Tsz + idxn)) * 2048 + dir * 1024 + r];
    // matvec over full h (t=0: h=0 contributes nothing)
    float acc = gcur;
    const float4* hb4 = (const float4*)hbuf;
#pragma unroll
    for (int i = 0; i < MR_VF4; ++i) {
      float4 hh = hb4[i], w = wv[i];
      acc = fmaf(hh.x, w.x, acc); acc = fmaf(hh.y, w.y, acc);
      acc = fmaf(hh.z, w.z, acc); acc = fmaf(hh.w, w.w, acc);
    }
#pragma unroll
    for (int i = 0; i < MR_LF4; ++i) {
      float4 hh = hb4[MR_VF4 + i], w = wl[i * 512 + j];
      acc = fmaf(hh.x, w.x, acc); acc = fmaf(hh.y, w.y, acc);
      acc = fmaf(hh.z, w.z, acc); acc = fmaf(hh.w, w.w, acc);
    }
#pragma unroll
    for (int i = 0; i < MR_TF4; ++i) {
      float4 hh = hb4[MR_VF4 + MR_LF4 + i];
      float4 w = *(const float4*)&Wr[(MR_VF4 + MR_LF4 + i) * 4];
      acc = fmaf(hh.x, w.x, acc); acc = fmaf(hh.y, w.y, acc);
      acc = fmaf(hh.z, w.z, acc); acc = fmaf(hh.w, w.w, acc);
    }
    gbuf[j] = (gc == 2) ? tanhf(acc) : sigm(acc);
    __syncthreads();
    if (j < 128) {
      float si = gbuf[ul], sf = gbuf[128 + ul], tg = gbuf[256 + ul], so = gbuf[384 + ul];
      c = sf * c + si * tg;
      float hn = so * tanhf(c);
      if (t + 1 < len) {
        union { float f; unsigned u; } cv; cv.f = hn;
        unsigned long long pk =
            ((unsigned long long)(unsigned)(t + 1) << 32) | (unsigned long long)cv.u;
        if (fast)
          __hip_atomic_store(&selfD[(t & 1) * 128 + ul], pk,
                             __ATOMIC_RELAXED, __HIP_MEMORY_SCOPE_WORKGROUP);
        else
          __hip_atomic_store(&selfD[(t & 1) * 128 + ul], pk,
                             __ATOMIC_RELAXED, __HIP_MEMORY_SCOPE_AGENT);
      }
      lstm_out[((size_t)(b * Tsz + idx)) * 512 + obase + ul] = hn;
      hbuf[half * 128 + ul] = hn;
      if (t + 1 < len) {
        unsigned long long pv; int guard = 0;
        if (fast) {
          for (;;) {
            pv = l2_poll(&partD[(t & 1) * 128 + ul]);
            if ((unsigned)(pv >> 32) == (unsigned)(t + 1)) break;
            if (++guard > (1 << 22)) break;   // watchdog
          }
        } else {
          for (;;) {
            pv = __hip_atomic_load(&partD[(t & 1) * 128 + ul],
                                   __ATOMIC_RELAXED, __HIP_MEMORY_SCOPE_AGENT);
            if ((unsigned)(pv >> 32) == (unsigned)(t + 1)) break;
            if (++guard > (1 << 22)) break;   // watchdog
            __builtin_amdgcn_s_sleep(1);
          }
        }
        union { unsigned u; float f; } hv; hv.u = (unsigned)(pv & 0xffffffffull);
        hbuf[(half ^ 1) * 128 + ul] = hv.f;
      }
    }
    __syncthreads();
    gcur = gnext;
  }
}

// ------------------------------- emit GEMM -----------------------------------
__global__ __launch_bounds__(256) void emit_kernel(
    const float* __restrict__ lstm_out, const float* __restrict__ Wout,
    const float* __restrict__ bout, float* __restrict__ emit) {
  int gid = blockIdx.x * 256 + threadIdx.x;      // NROW*32 threads
  int m = gid >> 5, j = gid & 31;
  if (j >= 20) return;
  const float4* xr = (const float4*)&lstm_out[(size_t)m * 512];
  const float4* wr = (const float4*)&Wout[(size_t)j * 512];
  float acc = bout[j];
#pragma unroll 8
  for (int i = 0; i < 128; ++i) {
    float4 x = xr[i], w = wr[i];
    acc += x.x * w.x + x.y * w.y + x.z * w.z + x.w * w.w;
  }
  emit[(size_t)m * 20 + j] = acc;
}

// ------------------------------- Viterbi -------------------------------------
__global__ __launch_bounds__(64) void viterbi_kernel(
    const int* __restrict__ lengths, const float* __restrict__ emit,
    const float* __restrict__ trans, int* __restrict__ out) {
  const int b = blockIdx.x, j = threadIdx.x;
  const int len = lengths[b];
  __shared__ float tr[400];
  __shared__ float alpha[20];
  __shared__ float fin[20];
  __shared__ unsigned char bp[256][20];
  for (int i = j; i < 400; i += 64) tr[i] = trans[i];
  __syncthreads();
  if (j < 20) alpha[j] = tr[18 * 20 + j] + emit[(size_t)(b * Tsz) * 20 + j];
  __syncthreads();
  for (int t = 1; t < len; ++t) {
    float best = 0.f; int bi = 0;
    if (j < 20) {
      best = alpha[0] + tr[j];
#pragma unroll
      for (int i = 1; i < 20; ++i) {
        float s = alpha[i] + tr[i * 20 + j];
        if (s > best) { best = s; bi = i; }
      }
      best += emit[((size_t)(b * Tsz + t)) * 20 + j];
    }
    __syncthreads();
    if (j < 20) { alpha[j] = best; bp[t][j] = (unsigned char)bi; }
    __syncthreads();
  }
  if (j < 20) fin[j] = alpha[j] + tr[j * 20 + 19];
  __syncthreads();
  if (j == 0) {
    float best = fin[0]; int tag = 0;
    for (int i = 1; i < 20; ++i) if (fin[i] > best) { best = fin[i]; tag = i; }
    out[b * Tsz + len - 1] = tag;
    for (int t = len - 1; t >= 1; --t) { tag = bp[t][tag]; out[b * Tsz + t - 1] = tag; }
  }
  for (int t = len + j; t < Tsz; t += 64) out[b * Tsz + t] = 0;
}

// ------------------------------- launcher ------------------------------------
extern "C" void kernel_launch(void* const* d_in, const int* in_sizes, int n_in,
                              void* d_out, int out_size, void* d_ws, size_t ws_size,
                              hipStream_t stream) {
  const int*   char_in = (const int*)d_in[0];
  const int*   pos_in  = (const int*)d_in[1];
  const int*   tag_in  = (const int*)d_in[2];
  const int*   lengths = (const int*)d_in[3];
  // d_in[4] = mask: recomputed from lengths, unused.
  const float* ce      = (const float*)d_in[5];
  const float* pe      = (const float*)d_in[6];
  const float* te      = (const float*)d_in[7];
  const float* pWih_f  = (const float*)d_in[8];
  const float* pWhh_f  = (const float*)d_in[9];
  const float* pb_f    = (const float*)d_in[10];
  const float* pWih_b  = (const float*)d_in[11];
  const float* pWhh_b  = (const float*)d_in[12];
  const float* pb_b    = (const float*)d_in[13];
  const float* mWih_f  = (const float*)d_in[14];
  const float* mWhh_f  = (const float*)d_in[15];
  const float* mb_f    = (const float*)d_in[16];
  const float* mWih_b  = (const float*)d_in[17];
  const float* mWhh_b  = (const float*)d_in[18];
  const float* mb_b    = (const float*)d_in[19];
  const float* W_out   = (const float*)d_in[20];
  const float* b_out   = (const float*)d_in[21];
  const float* trans   = (const float*)d_in[22];

  float* ws = (float*)d_ws;
  const size_t EMB     = 0;                          // 16384*640
  const size_t LSTMOUT = EMB + (size_t)NROW * 640;   // 16384*512
  const size_t EMIT    = LSTMOUT + (size_t)NROW * 512;
  const size_t HX      = EMIT + (size_t)NROW * 20;   // 256 * HX_STRIDE ull
  const size_t XINFO   = HX + 256 * HX_STRIDE * 2;   // 256 ull
  const size_t TBUF    = XINFO + 256 * 2;            // 16384*128
  const size_t GPOS    = TBUF + (size_t)NROW * 128;  // 16384*1024
  const size_t GMAIN   = TBUF;                       // 16384*2048 (overlaps)

  // clear exchange + probe + xinfo (stale tags must never match)
  hipMemsetAsync(ws + HX, 0, (256 * HX_STRIDE + 256) * sizeof(unsigned long long),
                 stream);

  gather_kernel<<<8192, 256, 0, stream>>>(char_in, pos_in, tag_in, ce, pe, te,
                                          ws + TBUF, ws + EMB);

  gemm_nt<<<dim3(4, 128), 256, 0, stream>>>(ws + TBUF, 128, pWih_f, 128, pb_f,
                                            ws + GPOS, 1024, 0, 128);
  gemm_nt<<<dim3(4, 128), 256, 0, stream>>>(ws + TBUF, 128, pWih_b, 128, pb_b,
                                            ws + GPOS, 1024, 512, 128);

  pos_rec<<<128, 512, 0, stream>>>(lengths, ws + GPOS, pWhh_f, pWhh_b, ws + EMB);

  gemm_nt<<<dim3(8, 128), 256, 0, stream>>>(ws + EMB, 640, mWih_f, 640, mb_f,
                                            ws + GMAIN, 2048, 0, 640);
  gemm_nt<<<dim3(8, 128), 256, 0, stream>>>(ws + EMB, 640, mWih_b, 640, mb_b,
                                            ws + GMAIN, 2048, 1024, 640);

  // LDS: 19*512*16 (weights) + 256*4 + 512*4 = 158720 B (<= 160 KiB)
  const int SMEM = MR_LF4 * 512 * 16 + 256 * 4 + 512 * 4;
  hipFuncSetAttribute((const void*)main_rec,
                      hipFuncAttributeMaxDynamicSharedMemorySize, SMEM);
  main_rec<<<256, 512, SMEM, stream>>>(lengths, ws + GMAIN, mWhh_f, mWhh_b,
                                       ws + LSTMOUT,
                                       (unsigned long long*)(ws + HX),
                                       (unsigned long long*)(ws + XINFO));

  emit_kernel<<<2048, 256, 0, stream>>>(ws + LSTMOUT, W_out, b_out, ws + EMIT);

  viterbi_kernel<<<64, 64, 0, stream>>>(lengths, ws + EMIT, trans, (int*)d_out);
}

// Round 13
// 1302.833 us; speedup vs baseline: 1.4727x; 1.4727x over previous
//
#include <hip/hip_runtime.h>
#include <hip/hip_bf16.h>
#include <math.h>

// ---------------------------------------------------------------------------
// BiLSTM-CRF, fp32 end-to-end (GEMMs via bf16x3-split MFMA, fp32 accumulate).
// Sizes: B=64 T=256 CHAR_E=256 POS_E=128 Hp=128, Hm=256, Dm=640, LBL=20.
// R13: (1) main_rec/pos_rec = R7/R11-exact (642us; XCD fast-path machinery
// removed after 3 failed probe designs -> plain-store/sc0 visibility across
// CUs never materializes). (2) gemm_mfma: C = A.W^T + bias via
// mfma_f32_16x16x32_bf16 with hi/lo split (hi.hi + hi.lo + lo.hi), fp32 acc.
// Error ~1e-5 rel << Viterbi argmax gaps. Layouts per m89/m91-verified:
// A[i][k]: i=lane&15, k=(lane>>4)*8+j ; B[k][j]: j=lane&15 (W rows direct);
// D: col=lane&15, row=(lane>>4)*4+reg.
// ---------------------------------------------------------------------------

#define Bsz 64
#define Tsz 256
#define NROW 16384        // B*T

__device__ __forceinline__ float sigm(float x) { return 1.f / (1.f + expf(-x)); }

#define PIN4(v) asm volatile("" : "+v"((v).x), "+v"((v).y), "+v"((v).z), "+v"((v).w))

typedef float f32x4 __attribute__((ext_vector_type(4)));
typedef short short8 __attribute__((ext_vector_type(8)));

// fp32 -> (bf16 hi, bf16 lo), RNE both. Finite inputs only.
__device__ __forceinline__ void bf16split(float f, ushort& h, ushort& l) {
  unsigned u = __float_as_uint(f);
  unsigned hh = (u + 0x7FFFu + ((u >> 16) & 1u)) >> 16;
  h = (ushort)hh;
  float hf = __uint_as_float(hh << 16);
  unsigned v = __float_as_uint(f - hf);
  l = (ushort)((v + 0x7FFFu + ((v >> 16) & 1u)) >> 16);
}

// ------------------------- gather: embeddings --------------------------------
__global__ __launch_bounds__(256) void gather_kernel(
    const int* __restrict__ ci, const int* __restrict__ pi, const int* __restrict__ ti,
    const float* __restrict__ ce, const float* __restrict__ pe, const float* __restrict__ te,
    float* __restrict__ tbuf, float* __restrict__ emb) {
  int gid = blockIdx.x * 256 + threadIdx.x;     // NROW*128 threads
  int m = gid >> 7, s = gid & 127;
  if (s < 32) {
    ((float4*)&tbuf[(size_t)m * 128])[s] = ((const float4*)&te[(size_t)ti[m] * 128])[s];
  } else if (s < 96) {
    ((float4*)&emb[(size_t)m * 640])[s - 32] = ((const float4*)&ce[(size_t)ci[m] * 256])[s - 32];
  } else {
    ((float4*)&emb[(size_t)m * 640 + 256])[s - 96] = ((const float4*)&pe[(size_t)pi[m] * 128])[s - 96];
  }
}

// ---------------- MFMA GEMM: C[m, col0+n] = A[m,:].W[n,:] + bias[n] ----------
// A [M,lda] f32, W [N,ldb] f32 row-major. Tile 128x128, K_STEP=32, 256 thr
// (4 waves; wave w owns rows w*32..w*32+31 = 2 row-frags x 8 col-frags).
// bf16x3: acc += Ah.Wh + Ah.Wl + Al.Wh  (each mfma_f32_16x16x32_bf16).
__global__ __launch_bounds__(256) void gemm_mfma(
    const float* __restrict__ A, int lda,
    const float* __restrict__ W, int ldb,
    const float* __restrict__ bias,
    float* __restrict__ C, int ldc, int col0, int K) {
  __shared__ __align__(16) ushort Ah[128][40];
  __shared__ __align__(16) ushort Al[128][40];
  __shared__ __align__(16) ushort Bh[128][40];
  __shared__ __align__(16) ushort Bl[128][40];
  const int tid = threadIdx.x;
  const int lane = tid & 63, wv = tid >> 6;
  const int l15 = lane & 15, l8 = (lane >> 4) * 8;
  const int m0 = blockIdx.y * 128, n0 = blockIdx.x * 128;

  f32x4 acc[2][8] = {};
  for (int k0 = 0; k0 < K; k0 += 32) {
    // ---- stage + split: A[128][32] and W[128][32] -> hi/lo bf16 in LDS ----
#pragma unroll
    for (int rr = 0; rr < 4; ++rr) {
      int fi = tid + rr * 256;
      int row = fi >> 3, q4 = (fi & 7) * 4;
      float4 av = *(const float4*)&A[(size_t)(m0 + row) * lda + k0 + q4];
      ushort4 h, l;
      bf16split(av.x, h.x, l.x); bf16split(av.y, h.y, l.y);
      bf16split(av.z, h.z, l.z); bf16split(av.w, h.w, l.w);
      *(ushort4*)&Ah[row][q4] = h; *(ushort4*)&Al[row][q4] = l;
      float4 bv = *(const float4*)&W[(size_t)(n0 + row) * ldb + k0 + q4];
      bf16split(bv.x, h.x, l.x); bf16split(bv.y, h.y, l.y);
      bf16split(bv.z, h.z, l.z); bf16split(bv.w, h.w, l.w);
      *(ushort4*)&Bh[row][q4] = h; *(ushort4*)&Bl[row][q4] = l;
    }
    __syncthreads();
    // ---- compute ----
    short8 aH[2], aL[2];
#pragma unroll
    for (int f = 0; f < 2; ++f) {
      aH[f] = *(const short8*)&Ah[wv * 32 + f * 16 + l15][l8];
      aL[f] = *(const short8*)&Al[wv * 32 + f * 16 + l15][l8];
    }
#pragma unroll
    for (int fc = 0; fc < 8; ++fc) {
      short8 bH = *(const short8*)&Bh[fc * 16 + l15][l8];
      short8 bL = *(const short8*)&Bl[fc * 16 + l15][l8];
#pragma unroll
      for (int f = 0; f < 2; ++f) {
        acc[f][fc] = __builtin_amdgcn_mfma_f32_16x16x32_bf16(aH[f], bH, acc[f][fc], 0, 0, 0);
        acc[f][fc] = __builtin_amdgcn_mfma_f32_16x16x32_bf16(aH[f], bL, acc[f][fc], 0, 0, 0);
        acc[f][fc] = __builtin_amdgcn_mfma_f32_16x16x32_bf16(aL[f], bH, acc[f][fc], 0, 0, 0);
      }
    }
    __syncthreads();
  }
  // ---- epilogue: D row=(lane>>4)*4+q, col=lane&15 ----
  const int l4 = lane >> 4;
#pragma unroll
  for (int f = 0; f < 2; ++f)
#pragma unroll
    for (int fc = 0; fc < 8; ++fc) {
      int col = fc * 16 + l15;
      float bs = bias[n0 + col];
#pragma unroll
      for (int q = 0; q < 4; ++q) {
        size_t row = m0 + wv * 32 + f * 16 + l4 * 4 + q;
        C[row * ldc + col0 + n0 + col] = acc[f][fc][q] + bs;
      }
    }
}

// --------------------------- pos BiLSTM recurrence ---------------------------
// 128 blocks (b, dir). 512 threads = 512 gate rows; Whh [512][128] pinned via
// asm-opaque (cures compiler loop-invariant-load sinking). R7-proven.
__global__ __launch_bounds__(512, 2) void pos_rec(
    const int* __restrict__ lengths, const float* __restrict__ gpos,
    const float* __restrict__ Wf, const float* __restrict__ Wb,
    float* __restrict__ emb) {
  const int blk = blockIdx.x;
  const int b = blk >> 1, dir = blk & 1;
  const int j = threadIdx.x;
  const int gc = j >> 7;
  const int len = lengths[b];
  const float* W = dir ? Wb : Wf;
  __shared__ __align__(16) float h[128];
  __shared__ float gbuf[512];
  float4 w4[32];
#pragma unroll
  for (int i = 0; i < 32; ++i) w4[i] = *(const float4*)&W[(size_t)j * 128 + i * 4];
#pragma unroll
  for (int i = 0; i < 32; ++i) PIN4(w4[i]);
  float c = 0.f;
  if (j < 128) h[j] = 0.f;
  __syncthreads();
  int idx0 = dir ? (len - 1) : 0;
  float gcur = gpos[((size_t)(b * Tsz + idx0)) * 1024 + dir * 512 + j];
  for (int t = 0; t < len; ++t) {
    const int idx = dir ? (len - 1 - t) : t;
    const int tn = (t + 1 < len) ? t + 1 : t;
    const int idxn = dir ? (len - 1 - tn) : tn;
    float gnext = gpos[((size_t)(b * Tsz + idxn)) * 1024 + dir * 512 + j];
    float acc = gcur;
    const float4* h4 = (const float4*)h;
#pragma unroll
    for (int i = 0; i < 32; ++i) {
      float4 hh = h4[i];
      acc = fmaf(hh.x, w4[i].x, acc); acc = fmaf(hh.y, w4[i].y, acc);
      acc = fmaf(hh.z, w4[i].z, acc); acc = fmaf(hh.w, w4[i].w, acc);
    }
    gbuf[j] = (gc == 2) ? tanhf(acc) : sigm(acc);
    __syncthreads();
    if (j < 128) {
      float si = gbuf[j], sf = gbuf[128 + j], tg = gbuf[256 + j], so = gbuf[384 + j];
      c = sf * c + si * tg;
      float hn = so * tanhf(c);
      h[j] = hn;
      emb[((size_t)(b * Tsz + idx)) * 640 + 384 + dir * 128 + j] = hn;
    }
    __syncthreads();
    gcur = gnext;
  }
}

// --------------------------- main BiLSTM recurrence --------------------------
// R7-EXACT (642us proven). 256 blocks: blk = b*4 + dir*2 + half; partner=blk^1.
// Weights/thread: 40 f4 PINNED VGPR, 19 f4 LDS, 5 f4 compiler-choice.
// Exchange: packed (tag<<32|bits) relaxed agent atomics, parity dbuf.
#define MR_VF4 40
#define MR_LF4 19
#define MR_TF4 5
#define HX_STRIDE 256      // ull per block (2 parity slots x 128)
__global__ __launch_bounds__(512, 2) void main_rec(
    const int* __restrict__ lengths, const float* __restrict__ gmain,
    const float* __restrict__ Wf, const float* __restrict__ Wb,
    float* __restrict__ lstm_out, unsigned long long* __restrict__ hx) {
  extern __shared__ float smem[];
  float4* wl  = (float4*)smem;                    // [MR_LF4*512] float4
  float* hbuf = smem + MR_LF4 * 512 * 4;          // 256 (full h, absolute idx)
  float* gbuf = hbuf + 256;                       // 512

  const int blk = blockIdx.x;
  const int b = blk >> 2, dir = (blk >> 1) & 1, half = blk & 1;
  const int j = threadIdx.x;
  const int gc = j >> 7, ul = j & 127;
  const int r = gc * 256 + half * 128 + ul;        // gate row in [0,1024)
  const int len = lengths[b];
  const float* Wr = (dir ? Wb : Wf) + (size_t)r * 256;

  float4 wv[MR_VF4];
#pragma unroll
  for (int i = 0; i < MR_VF4; ++i) wv[i] = *(const float4*)&Wr[i * 4];
#pragma unroll
  for (int i = 0; i < MR_VF4; ++i) PIN4(wv[i]);
#pragma unroll
  for (int i = 0; i < MR_LF4; ++i) wl[i * 512 + j] = *(const float4*)&Wr[(MR_VF4 + i) * 4];

  unsigned long long* selfD = hx + (size_t)blk * HX_STRIDE;
  unsigned long long* partD = hx + (size_t)(blk ^ 1) * HX_STRIDE;
  const int obase = dir * 256 + half * 128;

  float c = 0.f;
  if (j < 256) hbuf[j] = 0.f;
  __syncthreads();

  const int idx0 = dir ? (len - 1) : 0;
  float gcur = gmain[((size_t)(b * Tsz + idx0)) * 2048 + dir * 1024 + r];
  for (int t = 0; t < len; ++t) {
    const int idx = dir ? (len - 1 - t) : t;
    const int tn = (t + 1 < len) ? t + 1 : t;
    const int idxn = dir ? (len - 1 - tn) : tn;
    float gnext = gmain[((size_t)(b * Tsz + idxn)) * 2048 + dir * 1024 + r];
    // matvec over full h (t=0: h=0 contributes nothing)
    float acc = gcur;
    const float4* hb4 = (const float4*)hbuf;
#pragma unroll
    for (int i = 0; i < MR_VF4; ++i) {
      float4 hh = hb4[i], w = wv[i];
      acc = fmaf(hh.x, w.x, acc); acc = fmaf(hh.y, w.y, acc);
      acc = fmaf(hh.z, w.z, acc); acc = fmaf(hh.w, w.w, acc);
    }
#pragma unroll
    for (int i = 0; i < MR_LF4; ++i) {
      float4 hh = hb4[MR_VF4 + i], w = wl[i * 512 + j];
      acc = fmaf(hh.x, w.x, acc); acc = fmaf(hh.y, w.y, acc);
      acc = fmaf(hh.z, w.z, acc); acc = fmaf(hh.w, w.w, acc);
    }
#pragma unroll
    for (int i = 0; i < MR_TF4; ++i) {
      float4 hh = hb4[MR_VF4 + MR_LF4 + i];
      float4 w = *(const float4*)&Wr[(MR_VF4 + MR_LF4 + i) * 4];
      acc = fmaf(hh.x, w.x, acc); acc = fmaf(hh.y, w.y, acc);
      acc = fmaf(hh.z, w.z, acc); acc = fmaf(hh.w, w.w, acc);
    }
    gbuf[j] = (gc == 2) ? tanhf(acc) : sigm(acc);
    __syncthreads();
    if (j < 128) {
      float si = gbuf[ul], sf = gbuf[128 + ul], tg = gbuf[256 + ul], so = gbuf[384 + ul];
      c = sf * c + si * tg;
      float hn = so * tanhf(c);
      if (t + 1 < len) {
        union { float f; unsigned u; } cv; cv.f = hn;
        unsigned long long pk =
            ((unsigned long long)(unsigned)(t + 1) << 32) | (unsigned long long)cv.u;
        __hip_atomic_store(&selfD[(t & 1) * 128 + ul], pk,
                           __ATOMIC_RELAXED, __HIP_MEMORY_SCOPE_AGENT);
      }
      lstm_out[((size_t)(b * Tsz + idx)) * 512 + obase + ul] = hn;
      hbuf[half * 128 + ul] = hn;
      if (t + 1 < len) {
        unsigned long long pv; int guard = 0;
        for (;;) {
          pv = __hip_atomic_load(&partD[(t & 1) * 128 + ul],
                                 __ATOMIC_RELAXED, __HIP_MEMORY_SCOPE_AGENT);
          if ((unsigned)(pv >> 32) == (unsigned)(t + 1)) break;
          if (++guard > (1 << 22)) break;   // watchdog
          __builtin_amdgcn_s_sleep(1);
        }
        union { unsigned u; float f; } hv; hv.u = (unsigned)(pv & 0xffffffffull);
        hbuf[(half ^ 1) * 128 + ul] = hv.f;
      }
    }
    __syncthreads();
    gcur = gnext;
  }
}

// ------------------------------- emit GEMM -----------------------------------
__global__ __launch_bounds__(256) void emit_kernel(
    const float* __restrict__ lstm_out, const float* __restrict__ Wout,
    const float* __restrict__ bout, float* __restrict__ emit) {
  int gid = blockIdx.x * 256 + threadIdx.x;      // NROW*32 threads
  int m = gid >> 5, j = gid & 31;
  if (j >= 20) return;
  const float4* xr = (const float4*)&lstm_out[(size_t)m * 512];
  const float4* wr = (const float4*)&Wout[(size_t)j * 512];
  float acc = bout[j];
#pragma unroll 8
  for (int i = 0; i < 128; ++i) {
    float4 x = xr[i], w = wr[i];
    acc += x.x * w.x + x.y * w.y + x.z * w.z + x.w * w.w;
  }
  emit[(size_t)m * 20 + j] = acc;
}

// ------------------------------- Viterbi -------------------------------------
__global__ __launch_bounds__(64) void viterbi_kernel(
    const int* __restrict__ lengths, const float* __restrict__ emit,
    const float* __restrict__ trans, int* __restrict__ out) {
  const int b = blockIdx.x, j = threadIdx.x;
  const int len = lengths[b];
  __shared__ float tr[400];
  __shared__ float alpha[20];
  __shared__ float fin[20];
  __shared__ unsigned char bp[256][20];
  for (int i = j; i < 400; i += 64) tr[i] = trans[i];
  __syncthreads();
  if (j < 20) alpha[j] = tr[18 * 20 + j] + emit[(size_t)(b * Tsz) * 20 + j];
  __syncthreads();
  for (int t = 1; t < len; ++t) {
    float best = 0.f; int bi = 0;
    if (j < 20) {
      best = alpha[0] + tr[j];
#pragma unroll
      for (int i = 1; i < 20; ++i) {
        float s = alpha[i] + tr[i * 20 + j];
        if (s > best) { best = s; bi = i; }
      }
      best += emit[((size_t)(b * Tsz + t)) * 20 + j];
    }
    __syncthreads();
    if (j < 20) { alpha[j] = best; bp[t][j] = (unsigned char)bi; }
    __syncthreads();
  }
  if (j < 20) fin[j] = alpha[j] + tr[j * 20 + 19];
  __syncthreads();
  if (j == 0) {
    float best = fin[0]; int tag = 0;
    for (int i = 1; i < 20; ++i) if (fin[i] > best) { best = fin[i]; tag = i; }
    out[b * Tsz + len - 1] = tag;
    for (int t = len - 1; t >= 1; --t) { tag = bp[t][tag]; out[b * Tsz + t - 1] = tag; }
  }
  for (int t = len + j; t < Tsz; t += 64) out[b * Tsz + t] = 0;
}

// ------------------------------- launcher ------------------------------------
extern "C" void kernel_launch(void* const* d_in, const int* in_sizes, int n_in,
                              void* d_out, int out_size, void* d_ws, size_t ws_size,
                              hipStream_t stream) {
  const int*   char_in = (const int*)d_in[0];
  const int*   pos_in  = (const int*)d_in[1];
  const int*   tag_in  = (const int*)d_in[2];
  const int*   lengths = (const int*)d_in[3];
  // d_in[4] = mask: recomputed from lengths, unused.
  const float* ce      = (const float*)d_in[5];
  const float* pe      = (const float*)d_in[6];
  const float* te      = (const float*)d_in[7];
  const float* pWih_f  = (const float*)d_in[8];
  const float* pWhh_f  = (const float*)d_in[9];
  const float* pb_f    = (const float*)d_in[10];
  const float* pWih_b  = (const float*)d_in[11];
  const float* pWhh_b  = (const float*)d_in[12];
  const float* pb_b    = (const float*)d_in[13];
  const float* mWih_f  = (const float*)d_in[14];
  const float* mWhh_f  = (const float*)d_in[15];
  const float* mb_f    = (const float*)d_in[16];
  const float* mWih_b  = (const float*)d_in[17];
  const float* mWhh_b  = (const float*)d_in[18];
  const float* mb_b    = (const float*)d_in[19];
  const float* W_out   = (const float*)d_in[20];
  const float* b_out   = (const float*)d_in[21];
  const float* trans   = (const float*)d_in[22];

  float* ws = (float*)d_ws;
  const size_t EMB     = 0;                          // 16384*640
  const size_t LSTMOUT = EMB + (size_t)NROW * 640;   // 16384*512
  const size_t EMIT    = LSTMOUT + (size_t)NROW * 512;
  const size_t HX      = EMIT + (size_t)NROW * 20;   // 256 * HX_STRIDE ull
  const size_t TBUF    = HX + 256 * HX_STRIDE * 2;   // 16384*128
  const size_t GPOS    = TBUF + (size_t)NROW * 128;  // 16384*1024
  const size_t GMAIN   = TBUF;                       // 16384*2048 (overlaps)

  // clear exchange region (stale tags must never match)
  hipMemsetAsync(ws + HX, 0, 256 * HX_STRIDE * sizeof(unsigned long long), stream);

  gather_kernel<<<8192, 256, 0, stream>>>(char_in, pos_in, tag_in, ce, pe, te,
                                          ws + TBUF, ws + EMB);

  // pos input GEMMs: [16384,128] @ [512,128]^T (+bias), out stride 1024
  gemm_mfma<<<dim3(4, 128), 256, 0, stream>>>(ws + TBUF, 128, pWih_f, 128, pb_f,
                                              ws + GPOS, 1024, 0, 128);
  gemm_mfma<<<dim3(4, 128), 256, 0, stream>>>(ws + TBUF, 128, pWih_b, 128, pb_b,
                                              ws + GPOS, 1024, 512, 128);

  pos_rec<<<128, 512, 0, stream>>>(lengths, ws + GPOS, pWhh_f, pWhh_b, ws + EMB);

  // main input GEMMs: [16384,640] @ [1024,640]^T (+bias), out stride 2048
  gemm_mfma<<<dim3(8, 128), 256, 0, stream>>>(ws + EMB, 640, mWih_f, 640, mb_f,
                                              ws + GMAIN, 2048, 0, 640);
  gemm_mfma<<<dim3(8, 128), 256, 0, stream>>>(ws + EMB, 640, mWih_b, 640, mb_b,
                                              ws + GMAIN, 2048, 1024, 640);

  // LDS: 19*512*16 (weights) + 256*4 + 512*4 = 158720 B (<= 160 KiB)
  const int SMEM = MR_LF4 * 512 * 16 + 256 * 4 + 512 * 4;
  hipFuncSetAttribute((const void*)main_rec,
                      hipFuncAttributeMaxDynamicSharedMemorySize, SMEM);
  main_rec<<<256, 512, SMEM, stream>>>(lengths, ws + GMAIN, mWhh_f, mWhh_b,
                                       ws + LSTMOUT, (unsigned long long*)(ws + HX));

  emit_kernel<<<2048, 256, 0, stream>>>(ws + LSTMOUT, W_out, b_out, ws + EMIT);

  viterbi_kernel<<<64, 64, 0, stream>>>(lengths, ws + EMIT, trans, (int*)d_out);
}

// Round 14
// 1266.096 us; speedup vs baseline: 1.5154x; 1.0290x over previous
//
#include <hip/hip_runtime.h>
#include <hip/hip_bf16.h>
#include <math.h>

// ---------------------------------------------------------------------------
// BiLSTM-CRF, fp32 end-to-end (GEMMs via bf16x3-split MFMA, fp32 accumulate).
// Sizes: B=64 T=256 CHAR_E=256 POS_E=128 Hp=128, Hm=256, Dm=640, LBL=20.
// R14: GEMM restructure. R13's gemm was LDS-read + split-VALU bound (W split
// recomputed 128x per m-tile). Now: (1) operands pre-split to bf16 hi/lo ONCE
// (wsplit4 for W; gather/pos_rec write split A directly); (2) 512x128 tile,
// 512 thr, wave = 4 rowfrags x 8 colfrags (B-frag reads amortized 4x rows);
// (3) reg-buffered staging hides global latency; (4) f/b merged per launch.
// Accumulation order identical to R13 -> bit-identical gmain -> tags exact.
// main_rec/pos_rec cores = R7-exact (proven).
// ---------------------------------------------------------------------------

#define Bsz 64
#define Tsz 256
#define NROW 16384        // B*T

__device__ __forceinline__ float sigm(float x) { return 1.f / (1.f + expf(-x)); }

#define PIN4(v) asm volatile("" : "+v"((v).x), "+v"((v).y), "+v"((v).z), "+v"((v).w))

typedef float f32x4 __attribute__((ext_vector_type(4)));
typedef short short8 __attribute__((ext_vector_type(8)));
typedef unsigned short u16;
typedef u16 u16x8 __attribute__((ext_vector_type(8)));

// fp32 -> (bf16 hi, bf16 lo), RNE both. Finite inputs only. (R13-proven)
__device__ __forceinline__ void bf16split(float f, u16& h, u16& l) {
  unsigned u = __float_as_uint(f);
  unsigned hh = (u + 0x7FFFu + ((u >> 16) & 1u)) >> 16;
  h = (u16)hh;
  float hf = __uint_as_float(hh << 16);
  unsigned v = __float_as_uint(f - hf);
  l = (u16)((v + 0x7FFFu + ((v >> 16) & 1u)) >> 16);
}

// --------------------- weight pre-split (4 matrices, once) -------------------
__global__ __launch_bounds__(256) void wsplit4(
    const float* __restrict__ s0, u16* __restrict__ h0, u16* __restrict__ l0, int n0,
    const float* __restrict__ s1, u16* __restrict__ h1, u16* __restrict__ l1, int n1,
    const float* __restrict__ s2, u16* __restrict__ h2, u16* __restrict__ l2, int n2,
    const float* __restrict__ s3, u16* __restrict__ h3, u16* __restrict__ l3, int n3) {
  int i = (blockIdx.x * 256 + threadIdx.x) * 4;
  const float* s; u16 *h, *l;
  if (i < n0) { s = s0; h = h0; l = l0; }
  else if ((i -= n0) < n1) { s = s1; h = h1; l = l1; }
  else if ((i -= n1) < n2) { s = s2; h = h2; l = l2; }
  else if ((i -= n2) < n3) { s = s3; h = h3; l = l3; }
  else return;
  float4 v = *(const float4*)&s[i];
  ushort4 hh, ll;
  bf16split(v.x, hh.x, ll.x); bf16split(v.y, hh.y, ll.y);
  bf16split(v.z, hh.z, ll.z); bf16split(v.w, hh.w, ll.w);
  *(ushort4*)&h[i] = hh; *(ushort4*)&l[i] = ll;
}

// ---------------- gather: embeddings -> pre-split bf16 hi/lo -----------------
__global__ __launch_bounds__(256) void gather_kernel(
    const int* __restrict__ ci, const int* __restrict__ pi, const int* __restrict__ ti,
    const float* __restrict__ ce, const float* __restrict__ pe, const float* __restrict__ te,
    u16* __restrict__ tbh, u16* __restrict__ tbl,
    u16* __restrict__ emh, u16* __restrict__ eml) {
  int gid = blockIdx.x * 256 + threadIdx.x;     // NROW*128 threads
  int m = gid >> 7, s = gid & 127;
  float4 v; size_t off; u16 *ph, *pl;
  if (s < 32) {
    v = ((const float4*)&te[(size_t)ti[m] * 128])[s];
    off = (size_t)m * 128 + s * 4; ph = tbh; pl = tbl;
  } else if (s < 96) {
    v = ((const float4*)&ce[(size_t)ci[m] * 256])[s - 32];
    off = (size_t)m * 640 + (s - 32) * 4; ph = emh; pl = eml;
  } else {
    v = ((const float4*)&pe[(size_t)pi[m] * 128])[s - 96];
    off = (size_t)m * 640 + 256 + (s - 96) * 4; ph = emh; pl = eml;
  }
  ushort4 h, l;
  bf16split(v.x, h.x, l.x); bf16split(v.y, h.y, l.y);
  bf16split(v.z, h.z, l.z); bf16split(v.w, h.w, l.w);
  *(ushort4*)&ph[off] = h; *(ushort4*)&pl[off] = l;
}

// ------- MFMA GEMM: C[m, n0+c] = A[m,:].W[n0+c,:] + bias   (pre-split) -------
// A hi/lo [M][K] u16; W hi/lo [2*Nh][K] u16 (f rows then b rows). Tile 512x128,
// 512 thr = 8 waves; wave w: rows w*64..+63 = 4 rowfrags x 8 colfrags.
// bf16x3: acc += Ah.Wh + Ah.Wl + Al.Wh per 32-k step (same order as R13).
#define GTM 512
#define GTN 128
__global__ __launch_bounds__(512) void gemm_bf16x3(
    const u16* __restrict__ Ah, const u16* __restrict__ Al,
    const u16* __restrict__ Wh, const u16* __restrict__ Wl,
    const float* __restrict__ biasF, const float* __restrict__ biasB,
    float* __restrict__ C, int ldc, int K, int NhB) {
  extern __shared__ u16 us[];
  u16* As_h = us;                        // [512][40]
  u16* As_l = us + 512 * 40;
  u16* Ws_h = us + 2 * 512 * 40;         // [128][40]
  u16* Ws_l = us + 2 * 512 * 40 + 128 * 40;
  const int tid = threadIdx.x;
  const int lane = tid & 63, wv = tid >> 6;
  const int l15 = lane & 15, l8 = (lane >> 4) * 8, l4 = lane >> 4;
  const int m0 = blockIdx.y * GTM;
  const int n0 = blockIdx.x * GTN;       // col into C / row into concat W
  const u16* WhS = Wh + (size_t)n0 * K;
  const u16* WlS = Wl + (size_t)n0 * K;
  const float* bias = (blockIdx.x < (unsigned)NhB) ? (biasF + n0)
                                                   : (biasB + (n0 - NhB * GTN));
  const int arow = tid >> 2, aq = (tid & 3) * 8;   // staging coords

  u16x8 rA[4][2], rW[2];
#define LOAD_TILES(k0)                                                         \
  {                                                                            \
    _Pragma("unroll")                                                          \
    for (int r = 0; r < 4; ++r) {                                              \
      int row = arow + r * 128;                                                \
      rA[r][0] = *(const u16x8*)&Ah[(size_t)(m0 + row) * K + (k0) + aq];       \
      rA[r][1] = *(const u16x8*)&Al[(size_t)(m0 + row) * K + (k0) + aq];       \
    }                                                                          \
    rW[0] = *(const u16x8*)&WhS[(size_t)arow * K + (k0) + aq];                 \
    rW[1] = *(const u16x8*)&WlS[(size_t)arow * K + (k0) + aq];                 \
  }

  f32x4 acc[4][8] = {};
  LOAD_TILES(0);
  for (int k0 = 0; k0 < K; k0 += 32) {
#pragma unroll
    for (int r = 0; r < 4; ++r) {
      int row = arow + r * 128;
      *(u16x8*)&As_h[row * 40 + aq] = rA[r][0];
      *(u16x8*)&As_l[row * 40 + aq] = rA[r][1];
    }
    if (arow < 128) {
      *(u16x8*)&Ws_h[arow * 40 + aq] = rW[0];
      *(u16x8*)&Ws_l[arow * 40 + aq] = rW[1];
    }
    __syncthreads();
    if (k0 + 32 < K) LOAD_TILES(k0 + 32);
    short8 aH[4], aL[4];
#pragma unroll
    for (int fr = 0; fr < 4; ++fr) {
      aH[fr] = *(const short8*)&As_h[(wv * 64 + fr * 16 + l15) * 40 + l8];
      aL[fr] = *(const short8*)&As_l[(wv * 64 + fr * 16 + l15) * 40 + l8];
    }
#pragma unroll
    for (int cf = 0; cf < 8; ++cf) {
      short8 bH = *(const short8*)&Ws_h[(cf * 16 + l15) * 40 + l8];
      short8 bL = *(const short8*)&Ws_l[(cf * 16 + l15) * 40 + l8];
#pragma unroll
      for (int fr = 0; fr < 4; ++fr) {
        acc[fr][cf] = __builtin_amdgcn_mfma_f32_16x16x32_bf16(aH[fr], bH, acc[fr][cf], 0, 0, 0);
        acc[fr][cf] = __builtin_amdgcn_mfma_f32_16x16x32_bf16(aH[fr], bL, acc[fr][cf], 0, 0, 0);
        acc[fr][cf] = __builtin_amdgcn_mfma_f32_16x16x32_bf16(aL[fr], bH, acc[fr][cf], 0, 0, 0);
      }
    }
    __syncthreads();
  }
  // epilogue: D row=(lane>>4)*4+q, col=lane&15 (m89/m91 mapping)
#pragma unroll
  for (int fr = 0; fr < 4; ++fr)
#pragma unroll
    for (int cf = 0; cf < 8; ++cf) {
      int col = cf * 16 + l15;
      float bs = bias[col];
#pragma unroll
      for (int q = 0; q < 4; ++q) {
        size_t row = m0 + wv * 64 + fr * 16 + l4 * 4 + q;
        C[row * ldc + n0 + col] = acc[fr][cf][q] + bs;
      }
    }
#undef LOAD_TILES
}

// --------------------------- pos BiLSTM recurrence ---------------------------
// R7-exact core; output stores now write split bf16 hi/lo into emb buffers.
__global__ __launch_bounds__(512, 2) void pos_rec(
    const int* __restrict__ lengths, const float* __restrict__ gpos,
    const float* __restrict__ Wf, const float* __restrict__ Wb,
    u16* __restrict__ emh, u16* __restrict__ eml) {
  const int blk = blockIdx.x;
  const int b = blk >> 1, dir = blk & 1;
  const int j = threadIdx.x;
  const int gc = j >> 7;
  const int len = lengths[b];
  const float* W = dir ? Wb : Wf;
  __shared__ __align__(16) float h[128];
  __shared__ float gbuf[512];
  float4 w4[32];
#pragma unroll
  for (int i = 0; i < 32; ++i) w4[i] = *(const float4*)&W[(size_t)j * 128 + i * 4];
#pragma unroll
  for (int i = 0; i < 32; ++i) PIN4(w4[i]);
  float c = 0.f;
  if (j < 128) h[j] = 0.f;
  __syncthreads();
  int idx0 = dir ? (len - 1) : 0;
  float gcur = gpos[((size_t)(b * Tsz + idx0)) * 1024 + dir * 512 + j];
  for (int t = 0; t < len; ++t) {
    const int idx = dir ? (len - 1 - t) : t;
    const int tn = (t + 1 < len) ? t + 1 : t;
    const int idxn = dir ? (len - 1 - tn) : tn;
    float gnext = gpos[((size_t)(b * Tsz + idxn)) * 1024 + dir * 512 + j];
    float acc = gcur;
    const float4* h4 = (const float4*)h;
#pragma unroll
    for (int i = 0; i < 32; ++i) {
      float4 hh = h4[i];
      acc = fmaf(hh.x, w4[i].x, acc); acc = fmaf(hh.y, w4[i].y, acc);
      acc = fmaf(hh.z, w4[i].z, acc); acc = fmaf(hh.w, w4[i].w, acc);
    }
    gbuf[j] = (gc == 2) ? tanhf(acc) : sigm(acc);
    __syncthreads();
    if (j < 128) {
      float si = gbuf[j], sf = gbuf[128 + j], tg = gbuf[256 + j], so = gbuf[384 + j];
      c = sf * c + si * tg;
      float hn = so * tanhf(c);
      h[j] = hn;
      u16 hh2, hl2; bf16split(hn, hh2, hl2);
      size_t eo = ((size_t)(b * Tsz + idx)) * 640 + 384 + dir * 128 + j;
      emh[eo] = hh2; eml[eo] = hl2;
    }
    __syncthreads();
    gcur = gnext;
  }
}

// --------------------------- main BiLSTM recurrence --------------------------
// R7-EXACT (proven). 256 blocks: blk = b*4 + dir*2 + half; partner = blk^1.
// Weights/thread: 40 f4 PINNED VGPR, 19 f4 LDS, 5 f4 compiler-choice.
// Exchange: packed (tag<<32|bits) relaxed agent atomics, parity dbuf.
#define MR_VF4 40
#define MR_LF4 19
#define MR_TF4 5
#define HX_STRIDE 256      // ull per block (2 parity slots x 128)
__global__ __launch_bounds__(512, 2) void main_rec(
    const int* __restrict__ lengths, const float* __restrict__ gmain,
    const float* __restrict__ Wf, const float* __restrict__ Wb,
    float* __restrict__ lstm_out, unsigned long long* __restrict__ hx) {
  extern __shared__ float smem[];
  float4* wl  = (float4*)smem;                    // [MR_LF4*512] float4
  float* hbuf = smem + MR_LF4 * 512 * 4;          // 256 (full h, absolute idx)
  float* gbuf = hbuf + 256;                       // 512

  const int blk = blockIdx.x;
  const int b = blk >> 2, dir = (blk >> 1) & 1, half = blk & 1;
  const int j = threadIdx.x;
  const int gc = j >> 7, ul = j & 127;
  const int r = gc * 256 + half * 128 + ul;        // gate row in [0,1024)
  const int len = lengths[b];
  const float* Wr = (dir ? Wb : Wf) + (size_t)r * 256;

  float4 wv[MR_VF4];
#pragma unroll
  for (int i = 0; i < MR_VF4; ++i) wv[i] = *(const float4*)&Wr[i * 4];
#pragma unroll
  for (int i = 0; i < MR_VF4; ++i) PIN4(wv[i]);
#pragma unroll
  for (int i = 0; i < MR_LF4; ++i) wl[i * 512 + j] = *(const float4*)&Wr[(MR_VF4 + i) * 4];

  unsigned long long* selfD = hx + (size_t)blk * HX_STRIDE;
  unsigned long long* partD = hx + (size_t)(blk ^ 1) * HX_STRIDE;
  const int obase = dir * 256 + half * 128;

  float c = 0.f;
  if (j < 256) hbuf[j] = 0.f;
  __syncthreads();

  const int idx0 = dir ? (len - 1) : 0;
  float gcur = gmain[((size_t)(b * Tsz + idx0)) * 2048 + dir * 1024 + r];
  for (int t = 0; t < len; ++t) {
    const int idx = dir ? (len - 1 - t) : t;
    const int tn = (t + 1 < len) ? t + 1 : t;
    const int idxn = dir ? (len - 1 - tn) : tn;
    float gnext = gmain[((size_t)(b * Tsz + idxn)) * 2048 + dir * 1024 + r];
    // matvec over full h (t=0: h=0 contributes nothing)
    float acc = gcur;
    const float4* hb4 = (const float4*)hbuf;
#pragma unroll
    for (int i = 0; i < MR_VF4; ++i) {
      float4 hh = hb4[i], w = wv[i];
      acc = fmaf(hh.x, w.x, acc); acc = fmaf(hh.y, w.y, acc);
      acc = fmaf(hh.z, w.z, acc); acc = fmaf(hh.w, w.w, acc);
    }
#pragma unroll
    for (int i = 0; i < MR_LF4; ++i) {
      float4 hh = hb4[MR_VF4 + i], w = wl[i * 512 + j];
      acc = fmaf(hh.x, w.x, acc); acc = fmaf(hh.y, w.y, acc);
      acc = fmaf(hh.z, w.z, acc); acc = fmaf(hh.w, w.w, acc);
    }
#pragma unroll
    for (int i = 0; i < MR_TF4; ++i) {
      float4 hh = hb4[MR_VF4 + MR_LF4 + i];
      float4 w = *(const float4*)&Wr[(MR_VF4 + MR_LF4 + i) * 4];
      acc = fmaf(hh.x, w.x, acc); acc = fmaf(hh.y, w.y, acc);
      acc = fmaf(hh.z, w.z, acc); acc = fmaf(hh.w, w.w, acc);
    }
    gbuf[j] = (gc == 2) ? tanhf(acc) : sigm(acc);
    __syncthreads();
    if (j < 128) {
      float si = gbuf[ul], sf = gbuf[128 + ul], tg = gbuf[256 + ul], so = gbuf[384 + ul];
      c = sf * c + si * tg;
      float hn = so * tanhf(c);
      if (t + 1 < len) {
        union { float f; unsigned u; } cv; cv.f = hn;
        unsigned long long pk =
            ((unsigned long long)(unsigned)(t + 1) << 32) | (unsigned long long)cv.u;
        __hip_atomic_store(&selfD[(t & 1) * 128 + ul], pk,
                           __ATOMIC_RELAXED, __HIP_MEMORY_SCOPE_AGENT);
      }
      lstm_out[((size_t)(b * Tsz + idx)) * 512 + obase + ul] = hn;
      hbuf[half * 128 + ul] = hn;
      if (t + 1 < len) {
        unsigned long long pv; int guard = 0;
        for (;;) {
          pv = __hip_atomic_load(&partD[(t & 1) * 128 + ul],
                                 __ATOMIC_RELAXED, __HIP_MEMORY_SCOPE_AGENT);
          if ((unsigned)(pv >> 32) == (unsigned)(t + 1)) break;
          if (++guard > (1 << 22)) break;   // watchdog
          __builtin_amdgcn_s_sleep(1);
        }
        union { unsigned u; float f; } hv; hv.u = (unsigned)(pv & 0xffffffffull);
        hbuf[(half ^ 1) * 128 + ul] = hv.f;
      }
    }
    __syncthreads();
    gcur = gnext;
  }
}

// ------------------------------- emit GEMM -----------------------------------
__global__ __launch_bounds__(256) void emit_kernel(
    const float* __restrict__ lstm_out, const float* __restrict__ Wout,
    const float* __restrict__ bout, float* __restrict__ emit) {
  int gid = blockIdx.x * 256 + threadIdx.x;      // NROW*32 threads
  int m = gid >> 5, j = gid & 31;
  if (j >= 20) return;
  const float4* xr = (const float4*)&lstm_out[(size_t)m * 512];
  const float4* wr = (const float4*)&Wout[(size_t)j * 512];
  float acc = bout[j];
#pragma unroll 8
  for (int i = 0; i < 128; ++i) {
    float4 x = xr[i], w = wr[i];
    acc += x.x * w.x + x.y * w.y + x.z * w.z + x.w * w.w;
  }
  emit[(size_t)m * 20 + j] = acc;
}

// ------------------------------- Viterbi -------------------------------------
__global__ __launch_bounds__(64) void viterbi_kernel(
    const int* __restrict__ lengths, const float* __restrict__ emit,
    const float* __restrict__ trans, int* __restrict__ out) {
  const int b = blockIdx.x, j = threadIdx.x;
  const int len = lengths[b];
  __shared__ float tr[400];
  __shared__ float alpha[20];
  __shared__ float fin[20];
  __shared__ unsigned char bp[256][20];
  for (int i = j; i < 400; i += 64) tr[i] = trans[i];
  __syncthreads();
  if (j < 20) alpha[j] = tr[18 * 20 + j] + emit[(size_t)(b * Tsz) * 20 + j];
  __syncthreads();
  for (int t = 1; t < len; ++t) {
    float best = 0.f; int bi = 0;
    if (j < 20) {
      best = alpha[0] + tr[j];
#pragma unroll
      for (int i = 1; i < 20; ++i) {
        float s = alpha[i] + tr[i * 20 + j];
        if (s > best) { best = s; bi = i; }
      }
      best += emit[((size_t)(b * Tsz + t)) * 20 + j];
    }
    __syncthreads();
    if (j < 20) { alpha[j] = best; bp[t][j] = (unsigned char)bi; }
    __syncthreads();
  }
  if (j < 20) fin[j] = alpha[j] + tr[j * 20 + 19];
  __syncthreads();
  if (j == 0) {
    float best = fin[0]; int tag = 0;
    for (int i = 1; i < 20; ++i) if (fin[i] > best) { best = fin[i]; tag = i; }
    out[b * Tsz + len - 1] = tag;
    for (int t = len - 1; t >= 1; --t) { tag = bp[t][tag]; out[b * Tsz + t - 1] = tag; }
  }
  for (int t = len + j; t < Tsz; t += 64) out[b * Tsz + t] = 0;
}

// ------------------------------- launcher ------------------------------------
extern "C" void kernel_launch(void* const* d_in, const int* in_sizes, int n_in,
                              void* d_out, int out_size, void* d_ws, size_t ws_size,
                              hipStream_t stream) {
  const int*   char_in = (const int*)d_in[0];
  const int*   pos_in  = (const int*)d_in[1];
  const int*   tag_in  = (const int*)d_in[2];
  const int*   lengths = (const int*)d_in[3];
  // d_in[4] = mask: recomputed from lengths, unused.
  const float* ce      = (const float*)d_in[5];
  const float* pe      = (const float*)d_in[6];
  const float* te      = (const float*)d_in[7];
  const float* pWih_f  = (const float*)d_in[8];
  const float* pWhh_f  = (const float*)d_in[9];
  const float* pb_f    = (const float*)d_in[10];
  const float* pWih_b  = (const float*)d_in[11];
  const float* pWhh_b  = (const float*)d_in[12];
  const float* pb_b    = (const float*)d_in[13];
  const float* mWih_f  = (const float*)d_in[14];
  const float* mWhh_f  = (const float*)d_in[15];
  const float* mb_f    = (const float*)d_in[16];
  const float* mWih_b  = (const float*)d_in[17];
  const float* mWhh_b  = (const float*)d_in[18];
  const float* mb_b    = (const float*)d_in[19];
  const float* W_out   = (const float*)d_in[20];
  const float* b_out   = (const float*)d_in[21];
  const float* trans   = (const float*)d_in[22];

  float* ws = (float*)d_ws;
  // ---- layout (float offsets), overlays verified by stage liveness ----
  const size_t WPH     = 0;                        //  65536 f (131072 u16: pos f|b)
  const size_t WPL     = 65536;                    //  65536
  const size_t WMH     = 131072;                   // 655360 f (main f|b)
  const size_t WML     = 786432;                   // 655360
  const size_t EMH     = 1441792;                  // 5242880 f (16384*640 u16)
  const size_t EML     = 6684672;                  // 5242880
  const size_t TBH     = 11927552;                 // 1048576 f (16384*128 u16)
  const size_t TBL     = 12976128;                 // 1048576
  const size_t GPOS    = 14024704;                 // 16777216 f
  const size_t GMAIN   = 11927552;                 // 33554432 f (overlays TB+GPOS+fresh)
  const size_t LSTMOUT = 1441792;                  // 8388608 f (overlays EMH/EML, dead)
  const size_t EMIT    = 9830400;                  // 327680 f (tail of EM region)
  const size_t HX      = 45481984;                 // 131072 f (fresh, after GMAIN)

  // clear exchange region (stale tags must never match)
  hipMemsetAsync(ws + HX, 0, HX_STRIDE * 256 * sizeof(unsigned long long), stream);

  // weight pre-split (once): pos f, pos b, main f, main b
  wsplit4<<<1408, 256, 0, stream>>>(
      pWih_f, (u16*)(ws + WPH),          (u16*)(ws + WPL),          65536,
      pWih_b, (u16*)(ws + WPH) + 65536,  (u16*)(ws + WPL) + 65536,  65536,
      mWih_f, (u16*)(ws + WMH),          (u16*)(ws + WML),          655360,
      mWih_b, (u16*)(ws + WMH) + 655360, (u16*)(ws + WML) + 655360, 655360);

  gather_kernel<<<8192, 256, 0, stream>>>(char_in, pos_in, tag_in, ce, pe, te,
                                          (u16*)(ws + TBH), (u16*)(ws + TBL),
                                          (u16*)(ws + EMH), (u16*)(ws + EML));

  const int GSMEM = (2 * 512 * 40 + 2 * 128 * 40) * 2;   // 102400 B
  hipFuncSetAttribute((const void*)gemm_bf16x3,
                      hipFuncAttributeMaxDynamicSharedMemorySize, GSMEM);

  // pos input GEMM (f+b merged): [16384,128] x [1024,128]^T -> GPOS ldc 1024
  gemm_bf16x3<<<dim3(8, 32), 512, GSMEM, stream>>>(
      (u16*)(ws + TBH), (u16*)(ws + TBL),
      (u16*)(ws + WPH), (u16*)(ws + WPL),
      pb_f, pb_b, ws + GPOS, 1024, 128, 4);

  pos_rec<<<128, 512, 0, stream>>>(lengths, ws + GPOS, pWhh_f, pWhh_b,
                                   (u16*)(ws + EMH), (u16*)(ws + EML));

  // main input GEMM (f+b merged): [16384,640] x [2048,640]^T -> GMAIN ldc 2048
  gemm_bf16x3<<<dim3(16, 32), 512, GSMEM, stream>>>(
      (u16*)(ws + EMH), (u16*)(ws + EML),
      (u16*)(ws + WMH), (u16*)(ws + WML),
      mb_f, mb_b, ws + GMAIN, 2048, 640, 8);

  // LDS: 19*512*16 (weights) + 256*4 + 512*4 = 158720 B (<= 160 KiB)
  const int SMEM = MR_LF4 * 512 * 16 + 256 * 4 + 512 * 4;
  hipFuncSetAttribute((const void*)main_rec,
                      hipFuncAttributeMaxDynamicSharedMemorySize, SMEM);
  main_rec<<<256, 512, SMEM, stream>>>(lengths, ws + GMAIN, mWhh_f, mWhh_b,
                                       ws + LSTMOUT, (unsigned long long*)(ws + HX));

  emit_kernel<<<2048, 256, 0, stream>>>(ws + LSTMOUT, W_out, b_out, ws + EMIT);

  viterbi_kernel<<<64, 64, 0, stream>>>(lengths, ws + EMIT, trans, (int*)d_out);
}